// Round 11
// baseline (498.882 us; speedup 1.0000x reference)
//
#include <hip/hip_runtime.h>
#include <stdint.h>

#define SEQ    512
#define BATCH  1024
#define NTAG   54
#define TSTART 52
#define TSTOP  53
#define EMROW  (BATCH * NTAG)   // 55296 floats per timestep

// ---------------------------------------------------------------------------
// Linear-space CRF forward, 2 batch elements per wave (packed rows).
// Lane 32h+l (l<27) holds rows (2l,2l+1) of batch b0+h.
//   u[j] = exp(alpha[j] - esum*ln2)
//   step: u' = (sum_i E[j,i]*u[i]) * (exp(feat[j]) * 2^-e_lag)
//
// Round-11 changes (attacking the invariant ~900 cyc/step floor):
//  (1) prefetch distance 8 -> 16 (32-slot ring, s_waitcnt vmcnt(32)): if the
//      floor was marginal load latency vs pipeline slack, it vanishes.
//  (2) alds double-buffered by step parity: no LDS WAR on the chain.
//  (3) packed fp32: u stored duplicated (x,x,y,y) in LDS, E2[i]=(EXi,EYi)
//      float2, __builtin_elementwise_fma -> v_pk_fma_f32 (56 instead of 112
//      FMA issues; falls back to 2x v_fma with identical numerics).
// ---------------------------------------------------------------------------

typedef float f32x2 __attribute__((ext_vector_type(2)));

typedef const __attribute__((address_space(1))) void* gld_gptr;
typedef __attribute__((address_space(3))) void*       gld_lptr;

__device__ __forceinline__ void stage4(const float* g, float* l) {
    __builtin_amdgcn_global_load_lds((gld_gptr)g, (gld_lptr)l, 4, 0, 0);
}

#define STEP(o, INC) do {                                                     \
    float* sl_ = (float*)&flds[((o) + 16) & 31][0];                           \
    stage4(gp,      sl_);                                                     \
    stage4(gp + 54, sl_ + 64);                                                \
    gp += (INC);                                                              \
    asm volatile("s_waitcnt vmcnt(32)" ::: "memory");                         \
    const int par_ = (o) & 1;                                                 \
    *(float4*)&alds[par_][half][4 * l31] =                                    \
        make_float4(u2.x, u2.x, u2.y, u2.y);                                  \
    float2 fv_ = *(const float2*)&flds[(o)][half * 64 + rowb];                \
    float sc_  = __uint_as_float((unsigned)(127 - e_lagv) << 23);             \
    f32x2 ef2_; ef2_.x = __expf(fv_.x) * sc_; ef2_.y = __expf(fv_.y) * sc_;   \
    f32x2 aA_ = {0.f, 0.f}, aB_ = {0.f, 0.f};                                 \
    f32x2 aC_ = {0.f, 0.f}, aD_ = {0.f, 0.f};                                 \
    const float4* ap_ = (const float4*)&alds[par_][half][0];                  \
    _Pragma("unroll")                                                         \
    for (int g_ = 0; g_ < 28; g_ += 2) {                                      \
        float4 v0_ = ap_[g_];                                                 \
        f32x2 d0_; d0_.x = v0_.x; d0_.y = v0_.y;                              \
        f32x2 d1_; d1_.x = v0_.z; d1_.y = v0_.w;                              \
        aA_ = __builtin_elementwise_fma(E2[2*g_+0], d0_, aA_);                \
        aB_ = __builtin_elementwise_fma(E2[2*g_+1], d1_, aB_);                \
        float4 v1_ = ap_[g_ + 1];                                             \
        f32x2 d2_; d2_.x = v1_.x; d2_.y = v1_.y;                              \
        f32x2 d3_; d3_.x = v1_.z; d3_.y = v1_.w;                              \
        aC_ = __builtin_elementwise_fma(E2[2*g_+2], d2_, aC_);                \
        aD_ = __builtin_elementwise_fma(E2[2*g_+3], d3_, aD_);                \
    }                                                                         \
    f32x2 s2_ = (aA_ + aC_) + (aB_ + aD_);                                    \
    f32x2 un2_ = s2_ * ef2_;                                                  \
    bool upA_ = (curA & 1ull) != 0ull;                                        \
    bool upB_ = (curB & 1ull) != 0ull;                                        \
    bool upL_ = (half ? upB_ : upA_) && live;                                 \
    u2.x = upL_ ? un2_.x : u2.x;                                              \
    u2.y = upL_ ? un2_.y : u2.y;                                              \
    esum += upL_ ? e_lagv : 0;                                                \
    curA >>= 1; curB >>= 1;                                                   \
    int bA_ = __builtin_amdgcn_readlane(__float_as_int(u2.x), 0);             \
    int bB_ = __builtin_amdgcn_readlane(__float_as_int(u2.x), 32);            \
    int eA_ = (((bA_ >> 23) & 255) - 127);                                    \
    eA_ = eA_ < -40 ? -40 : (eA_ > 40 ? 40 : eA_);                            \
    int eB_ = (((bB_ >> 23) & 255) - 127);                                    \
    eB_ = eB_ < -40 ? -40 : (eB_ > 40 ? 40 : eB_);                            \
    e_lagv = half ? eB_ : eA_;                                                \
} while (0)

__global__ __launch_bounds__(64, 1) void crf_fwd_kernel(
    const float* __restrict__ em, const float* __restrict__ tr,
    const int* __restrict__ tags, const int* __restrict__ mask,
    float* __restrict__ part, int* __restrict__ msum)
{
    __shared__ float tlds[NTAG * NTAG];
    __shared__ __align__(16) float alds[2][2][128];   // [parity][half][dup u]
    __shared__ __align__(16) float flds[32][128];     // emission staging ring

    const int lane = threadIdx.x;     // 64-thread block = 1 wave
    for (int k = lane; k < NTAG * NTAG; k += 64) tlds[k] = tr[k];
    __syncthreads();

    const int  b0   = blockIdx.x * 2;
    const bool half = lane >= 32;
    const int  l31  = lane & 31;
    const int  rowb = 2 * l31;        // rows (rowb, rowb+1); l31>=27 = pad
    const bool live = l31 < 27;

    // --- E rows (two per lane), exp'd, packed (EX,EY), zero-padded, pinned --
    f32x2 E2[56];
    #pragma unroll
    for (int i = 0; i < 56; ++i) {
        float ex = (live && i < NTAG) ? __expf(tlds[(rowb    ) * NTAG + i]) : 0.f;
        float ey = (live && i < NTAG) ? __expf(tlds[(rowb + 1) * NTAG + i]) : 0.f;
        E2[i].x = ex; E2[i].y = ey;
        asm("" : "+v"(E2[i]));
    }
    float esx = live ? __expf(tlds[TSTOP * NTAG + rowb    ]) : 0.f;
    float esy = live ? __expf(tlds[TSTOP * NTAG + rowb + 1]) : 0.f;

    // =======================================================================
    // Prepass: gold + mask ballots for BOTH batch elements
    // =======================================================================
    float    gold2[2] = {0.f, 0.f};
    int      ms2[2]   = {0, 0};
    uint64_t BA[8], BB[8];
    #pragma unroll
    for (int h = 0; h < 2; ++h) {
        const int b2 = b0 + h;
        #pragma unroll
        for (int r = 0; r < 8; ++r) {
            int s  = r * 64 + lane;
            int tg = tags[s * BATCH + b2];
            int mk = mask[s * BATCH + b2];
            int tp = (s == 0) ? TSTART : tags[(s - 1) * BATCH + b2];
            float emv = em[(size_t)s * EMROW + (size_t)b2 * NTAG + tg];
            float trv = tlds[tg * NTAG + tp];
            float mf  = (s == 0) ? 1.f : (float)mk;
            gold2[h] = fmaf(trv + emv, mf, gold2[h]);
            ms2[h] += mk;
            uint64_t bl = __ballot(mk > 0);
            if (h == 0) BA[r] = bl; else BB[r] = bl;
        }
    }
    #pragma unroll
    for (int off = 32; off >= 1; off >>= 1) {
        gold2[0] += __shfl_xor(gold2[0], off);
        gold2[1] += __shfl_xor(gold2[1], off);
        ms2[0]   += __shfl_xor(ms2[0], off);
        ms2[1]   += __shfl_xor(ms2[1], off);
    }

    // =======================================================================
    // Serial forward recursion
    // =======================================================================
    f32x2 u2; u2.x = (l31 == TSTART / 2) ? 1.f : 0.f; u2.y = 0.f;
    int esum   = 0;
    int e_lagv = 0;

    asm volatile("s_waitcnt vmcnt(0)" ::: "memory");   // drain prepass VMEM

    // per-lane global src: row index = lane (clamped); batch b0; step 0
    const float* gp = em + (size_t)b0 * NTAG + (lane < NTAG ? lane : NTAG - 1);
    #pragma unroll
    for (int s = 0; s < 16; ++s) {     // prologue: stage steps 0..15 (32 ops)
        float* sl = (float*)&flds[s][0];
        stage4(gp,      sl);
        stage4(gp + 54, sl + 64);
        gp += EMROW;
    }                                   // gp -> step 16

    for (int c = 0; c < 8; ++c) {
        uint64_t curA = BA[0], curB = BB[0];
        for (int q = 0; q < 2; ++q) {
            const size_t incT = (c == 7 && q == 1) ? 0 : (size_t)EMROW;
            STEP( 0, EMROW); STEP( 1, EMROW); STEP( 2, EMROW); STEP( 3, EMROW);
            STEP( 4, EMROW); STEP( 5, EMROW); STEP( 6, EMROW); STEP( 7, EMROW);
            STEP( 8, EMROW); STEP( 9, EMROW); STEP(10, EMROW); STEP(11, EMROW);
            STEP(12, EMROW); STEP(13, EMROW); STEP(14, EMROW); STEP(15, incT);
            STEP(16, incT);  STEP(17, incT);  STEP(18, incT);  STEP(19, incT);
            STEP(20, incT);  STEP(21, incT);  STEP(22, incT);  STEP(23, incT);
            STEP(24, incT);  STEP(25, incT);  STEP(26, incT);  STEP(27, incT);
            STEP(28, incT);  STEP(29, incT);  STEP(30, incT);  STEP(31, incT);
        }
        #pragma unroll
        for (int r = 0; r < 7; ++r) { BA[r] = BA[r + 1]; BB[r] = BB[r + 1]; }
    }

    // --- final forward score per half ---
    float us = u2.x * esx + u2.y * esy;
    #pragma unroll
    for (int off = 16; off >= 1; off >>= 1) us += __shfl_xor(us, off);
    float fwd = __logf(us) + (float)esum * 0.69314718f;

    asm volatile("s_waitcnt vmcnt(0)" ::: "memory");   // clean counter state
    int   myb = half ? b0 + 1 : b0;
    int   mym = half ? ms2[1] : ms2[0];
    float myg = half ? gold2[1] : gold2[0];
    int li    = (mym > 0) ? (mym - 1) : 0;
    int ltag  = tags[li * BATCH + myb];
    myg += tlds[TSTOP * NTAG + ltag];

    if (l31 == 0) { part[myb] = fwd - myg; msum[myb] = mym; }
}

// ---------------------------------------------------------------------------
// Kernel 2: deterministic reduction  out = sum(part) / sum(msum)
// ---------------------------------------------------------------------------
__global__ __launch_bounds__(256) void crf_reduce_kernel(
    const float* __restrict__ part, const int* __restrict__ msum,
    float* __restrict__ out)
{
    const int tid = threadIdx.x;
    float s = 0.f;
    int   m = 0;
    for (int k = tid; k < BATCH; k += 256) { s += part[k]; m += msum[k]; }
    #pragma unroll
    for (int off = 32; off >= 1; off >>= 1) {
        s += __shfl_xor(s, off);
        m += __shfl_xor(m, off);
    }
    __shared__ float sl[4];
    __shared__ int   ml[4];
    if ((tid & 63) == 0) { sl[tid >> 6] = s; ml[tid >> 6] = m; }
    __syncthreads();
    if (tid == 0)
        out[0] = (sl[0] + sl[1] + sl[2] + sl[3]) /
                 (float)(ml[0] + ml[1] + ml[2] + ml[3]);
}

extern "C" void kernel_launch(void* const* d_in, const int* in_sizes, int n_in,
                              void* d_out, int out_size, void* d_ws, size_t ws_size,
                              hipStream_t stream)
{
    const float* em   = (const float*)d_in[0];
    const float* tr   = (const float*)d_in[1];
    const int*   tags = (const int*)d_in[2];
    const int*   mask = (const int*)d_in[3];

    float* part  = (float*)d_ws;
    int*   msumw = (int*)((char*)d_ws + BATCH * sizeof(float));
    float* out   = (float*)d_out;

    crf_fwd_kernel<<<BATCH / 2, 64, 0, stream>>>(em, tr, tags, mask, part, msumw);
    crf_reduce_kernel<<<1, 256, 0, stream>>>(part, msumw, out);
}

// Round 12
// 144.549 us; speedup vs baseline: 3.4513x; 3.4513x over previous
//
#include <hip/hip_runtime.h>
#include <stdint.h>

#define SEQ    512
#define BATCH  1024
#define NTAG   54
#define TSTART 52
#define TSTOP  53
#define NW     4
#define EMROW  (BATCH * NTAG)   // 55296 floats per timestep

// ---------------------------------------------------------------------------
// Linear-space CRF forward. wave = batch element, lane = tag j (54/64 live).
//   u[j] = exp(alpha[j] - esum*ln2)
//   step: u' = (sum_i E[j,i]*u[i]) * (exp(feat[j]) * 2^-e_lag)
//
// Round-12 rebuild (readlane broadcast, pressure- and schedule-clean):
//  * E[54] scalar VGPRs (demand ~93; r11's float2 E2[112] forced the spill).
//  * emission ring: global_load_lds, 32 slots, staged 16 ahead -> a slot is
//    overwritten 16 steps after its read (no race), nothing lives in VGPRs.
//  * ONE s_waitcnt vmcnt(8) per 8-step group; feat reads + exp hoisted to
//    group top (r7-r10's per-step memory-clobber asm serialized these into
//    the chain). Steps themselves are pure register ops.
//  * VALU broadcast (54 readlane+54 fma) because VALU is per-SIMD (4 waves
//    scale), unlike the shared per-CU LDS pipe.
// ---------------------------------------------------------------------------

typedef const __attribute__((address_space(1))) void* gld_gptr;
typedef __attribute__((address_space(3))) void*       gld_lptr;

__device__ __forceinline__ void stage4(const float* g, float* l) {
    __builtin_amdgcn_global_load_lds((gld_gptr)g, (gld_lptr)l, 4, 0, 0);
}

__global__ __launch_bounds__(64 * NW, 1) void crf_fwd_kernel(
    const float* __restrict__ em, const float* __restrict__ tr,
    const int* __restrict__ tags, const int* __restrict__ mask,
    float* __restrict__ part, int* __restrict__ msum)
{
    __shared__ float tlds[NTAG * NTAG];
    __shared__ __align__(16) float flds[NW][32][64];   // emission ring

    const int tid = threadIdx.x;
    for (int k = tid; k < NTAG * NTAG; k += 64 * NW) tlds[k] = tr[k];
    __syncthreads();

    const int wv   = tid >> 6;
    const int lane = tid & 63;
    const int b    = blockIdx.x * NW + wv;
    const size_t bT = (size_t)b * NTAG;

    // --- E = exp(trans) row of this lane, 54 scalar VGPRs ---
    float E[NTAG];
    #pragma unroll
    for (int i = 0; i < NTAG; ++i) {
        E[i] = (lane < NTAG) ? __expf(tlds[lane * NTAG + i]) : 0.f;
        asm("" : "+v"(E[i]));
    }
    float estop = (lane < NTAG) ? __expf(tlds[TSTOP * NTAG + lane]) : 0.f;

    // =======================================================================
    // Prepass: gold + mask ballots (lane l handles steps l, l+64, ...)
    // =======================================================================
    float    goldp = 0.f;
    int      msump = 0;
    uint64_t B[8];
    #pragma unroll
    for (int r = 0; r < 8; ++r) {
        int s  = r * 64 + lane;
        int tg = tags[s * BATCH + b];
        int mk = mask[s * BATCH + b];
        int tp = (s == 0) ? TSTART : tags[(s - 1) * BATCH + b];
        float emv = em[(size_t)s * EMROW + bT + tg];
        float trv = tlds[tg * NTAG + tp];
        float mf  = (s == 0) ? 1.f : (float)mk;
        goldp = fmaf(trv + emv, mf, goldp);
        msump += mk;
        B[r] = __ballot(mk > 0);
    }
    #pragma unroll
    for (int off = 32; off >= 1; off >>= 1) {
        goldp += __shfl_xor(goldp, off);
        msump += __shfl_xor(msump, off);
    }

    // =======================================================================
    // Serial forward recursion
    // =======================================================================
    float u     = (lane == TSTART) ? 1.f : 0.f;
    int   esum  = 0;
    int   e_lag = 0;

    asm volatile("s_waitcnt vmcnt(0)" ::: "memory");   // drain prepass VMEM

    const float* gbase = em + bT + (lane < NTAG ? lane : NTAG - 1);
    #pragma unroll
    for (int s = 0; s < 16; ++s)                        // stage steps 0..15
        stage4(gbase + (size_t)((unsigned)s * (unsigned)EMROW),
               (float*)&flds[wv][s][0]);

    for (int ch = 0; ch < 8; ++ch) {
        uint64_t cur = B[0];
        #pragma unroll
        for (int g = 0; g < 8; ++g) {
            const int gb = ch * 64 + g * 8;
            // this group's 8 slots landed (8 newer still in flight)
            asm volatile("s_waitcnt vmcnt(8)" ::: "memory");
            // hoist feat reads + exp off the chain
            float ef[8];
            #pragma unroll
            for (int k = 0; k < 8; ++k)
                ef[k] = __expf(flds[wv][(gb + k) & 31][lane]);
            // stage 16 ahead (slots (gb+16+k)&31 - disjoint from reads)
            #pragma unroll
            for (int k = 0; k < 8; ++k) {
                int ts = gb + 16 + k;
                ts = ts > SEQ - 1 ? SEQ - 1 : ts;       // tail: dummy restage
                stage4(gbase + (size_t)((unsigned)ts * (unsigned)EMROW),
                       (float*)&flds[wv][(gb + 16 + k) & 31][0]);
            }
            // 8 pure-register recursion steps
            #pragma unroll
            for (int k = 0; k < 8; ++k) {
                int uu = __float_as_int(u);
                float a0 = 0.f, a1 = 0.f, a2 = 0.f, a3 = 0.f;
                #pragma unroll
                for (int i = 0; i < 52; i += 4) {
                    a0 = fmaf(E[i+0], __int_as_float(__builtin_amdgcn_readlane(uu, i+0)), a0);
                    a1 = fmaf(E[i+1], __int_as_float(__builtin_amdgcn_readlane(uu, i+1)), a1);
                    a2 = fmaf(E[i+2], __int_as_float(__builtin_amdgcn_readlane(uu, i+2)), a2);
                    a3 = fmaf(E[i+3], __int_as_float(__builtin_amdgcn_readlane(uu, i+3)), a3);
                }
                a0 = fmaf(E[52], __int_as_float(__builtin_amdgcn_readlane(uu, 52)), a0);
                a1 = fmaf(E[53], __int_as_float(__builtin_amdgcn_readlane(uu, 53)), a1);
                float w  = (a0 + a1) + (a2 + a3);
                float un = w * (ef[k] * __uint_as_float((unsigned)(127 - e_lag) << 23));
                bool  up = ((cur & 1ull) != 0ull) && (lane < NTAG);
                u = up ? un : u;
                esum += up ? e_lag : 0;
                cur >>= 1;
                int ub = __builtin_amdgcn_readlane(__float_as_int(u), 0);
                int en = ((ub >> 23) & 255) - 127;
                e_lag = en < -40 ? -40 : (en > 40 ? 40 : en);
            }
        }
        #pragma unroll
        for (int r = 0; r < 7; ++r) B[r] = B[r + 1];
    }

    // --- final forward score: log(sum_j u[j]*exp(trans[STOP,j])) + esum*ln2 ---
    float us = u * estop;
    #pragma unroll
    for (int off = 32; off >= 1; off >>= 1) us += __shfl_xor(us, off);
    float fwd = __logf(us) + (float)esum * 0.69314718f;

    asm volatile("s_waitcnt vmcnt(0)" ::: "memory");   // clean counter state
    int li   = (msump > 0) ? (msump - 1) : 0;
    int ltag = tags[li * BATCH + b];
    float gold = goldp + tlds[TSTOP * NTAG + ltag];

    if (lane == 0) { part[b] = fwd - gold; msum[b] = msump; }
}

// ---------------------------------------------------------------------------
// Kernel 2: deterministic reduction  out = sum(part) / sum(msum)
// ---------------------------------------------------------------------------
__global__ __launch_bounds__(256) void crf_reduce_kernel(
    const float* __restrict__ part, const int* __restrict__ msum,
    float* __restrict__ out)
{
    const int tid = threadIdx.x;
    float s = 0.f;
    int   m = 0;
    for (int k = tid; k < BATCH; k += 256) { s += part[k]; m += msum[k]; }
    #pragma unroll
    for (int off = 32; off >= 1; off >>= 1) {
        s += __shfl_xor(s, off);
        m += __shfl_xor(m, off);
    }
    __shared__ float sl[4];
    __shared__ int   ml[4];
    if ((tid & 63) == 0) { sl[tid >> 6] = s; ml[tid >> 6] = m; }
    __syncthreads();
    if (tid == 0)
        out[0] = (sl[0] + sl[1] + sl[2] + sl[3]) /
                 (float)(ml[0] + ml[1] + ml[2] + ml[3]);
}

extern "C" void kernel_launch(void* const* d_in, const int* in_sizes, int n_in,
                              void* d_out, int out_size, void* d_ws, size_t ws_size,
                              hipStream_t stream)
{
    const float* em   = (const float*)d_in[0];
    const float* tr   = (const float*)d_in[1];
    const int*   tags = (const int*)d_in[2];
    const int*   mask = (const int*)d_in[3];

    float* part  = (float*)d_ws;
    int*   msumw = (int*)((char*)d_ws + BATCH * sizeof(float));
    float* out   = (float*)d_out;

    crf_fwd_kernel<<<BATCH / NW, 64 * NW, 0, stream>>>(em, tr, tags, mask, part, msumw);
    crf_reduce_kernel<<<1, 256, 0, stream>>>(part, msumw, out);
}

// Round 13
// 144.129 us; speedup vs baseline: 3.4613x; 1.0029x over previous
//
#include <hip/hip_runtime.h>
#include <stdint.h>

#define SEQ    512
#define BATCH  1024
#define NTAG   54
#define TSTART 52
#define TSTOP  53
#define NW     4
#define EMROW  (BATCH * NTAG)   // 55296 floats per timestep

// ---------------------------------------------------------------------------
// Linear-space CRF forward. wave = batch element, lane = tag j (54/64 live).
//   u[j] = exp(alpha[j] - esum*ln2)
//   step: u' = (sum_i E[j,i]*u[i]) * (exp(feat[j]) * 2^-e_lag)
//
// Round-13 change (ONLY the inner step body vs r12):
//   phase-split broadcast: all 54 v_readlane -> 54 SGPRs first (back-to-back
//   readlanes fill each other's VALU->SGPR wait-states), sched_barrier(0),
//   then all 54 v_fma reading retired SGPRs (zero wait-states). r12 paired
//   readlane;fma tightly -> ~4 cyc hazard x54 = the measured ~379 stall.
// Everything else identical to r12 (165 us, absmax 0.0): E[54] resident
// (VGPR=68), 32-slot global_load_lds ring staged 16 ahead, one vmcnt(8) +
// feat-exp hoist per 8-step group, ballot masks, prepass gold.
// ---------------------------------------------------------------------------

typedef const __attribute__((address_space(1))) void* gld_gptr;
typedef __attribute__((address_space(3))) void*       gld_lptr;

__device__ __forceinline__ void stage4(const float* g, float* l) {
    __builtin_amdgcn_global_load_lds((gld_gptr)g, (gld_lptr)l, 4, 0, 0);
}

__global__ __launch_bounds__(64 * NW, 1) void crf_fwd_kernel(
    const float* __restrict__ em, const float* __restrict__ tr,
    const int* __restrict__ tags, const int* __restrict__ mask,
    float* __restrict__ part, int* __restrict__ msum)
{
    __shared__ float tlds[NTAG * NTAG];
    __shared__ __align__(16) float flds[NW][32][64];   // emission ring

    const int tid = threadIdx.x;
    for (int k = tid; k < NTAG * NTAG; k += 64 * NW) tlds[k] = tr[k];
    __syncthreads();

    const int wv   = tid >> 6;
    const int lane = tid & 63;
    const int b    = blockIdx.x * NW + wv;
    const size_t bT = (size_t)b * NTAG;

    // --- E = exp(trans) row of this lane, 54 scalar VGPRs ---
    float E[NTAG];
    #pragma unroll
    for (int i = 0; i < NTAG; ++i) {
        E[i] = (lane < NTAG) ? __expf(tlds[lane * NTAG + i]) : 0.f;
        asm("" : "+v"(E[i]));
    }
    float estop = (lane < NTAG) ? __expf(tlds[TSTOP * NTAG + lane]) : 0.f;

    // =======================================================================
    // Prepass: gold + mask ballots (lane l handles steps l, l+64, ...)
    // =======================================================================
    float    goldp = 0.f;
    int      msump = 0;
    uint64_t B[8];
    #pragma unroll
    for (int r = 0; r < 8; ++r) {
        int s  = r * 64 + lane;
        int tg = tags[s * BATCH + b];
        int mk = mask[s * BATCH + b];
        int tp = (s == 0) ? TSTART : tags[(s - 1) * BATCH + b];
        float emv = em[(size_t)s * EMROW + bT + tg];
        float trv = tlds[tg * NTAG + tp];
        float mf  = (s == 0) ? 1.f : (float)mk;
        goldp = fmaf(trv + emv, mf, goldp);
        msump += mk;
        B[r] = __ballot(mk > 0);
    }
    #pragma unroll
    for (int off = 32; off >= 1; off >>= 1) {
        goldp += __shfl_xor(goldp, off);
        msump += __shfl_xor(msump, off);
    }

    // =======================================================================
    // Serial forward recursion
    // =======================================================================
    float u     = (lane == TSTART) ? 1.f : 0.f;
    int   esum  = 0;
    int   e_lag = 0;

    asm volatile("s_waitcnt vmcnt(0)" ::: "memory");   // drain prepass VMEM

    const float* gbase = em + bT + (lane < NTAG ? lane : NTAG - 1);
    #pragma unroll
    for (int s = 0; s < 16; ++s)                        // stage steps 0..15
        stage4(gbase + (size_t)((unsigned)s * (unsigned)EMROW),
               (float*)&flds[wv][s][0]);

    for (int ch = 0; ch < 8; ++ch) {
        uint64_t cur = B[0];
        #pragma unroll
        for (int g = 0; g < 8; ++g) {
            const int gb = ch * 64 + g * 8;
            // this group's 8 slots landed (8 newer still in flight)
            asm volatile("s_waitcnt vmcnt(8)" ::: "memory");
            // hoist feat reads + exp off the chain
            float ef[8];
            #pragma unroll
            for (int k = 0; k < 8; ++k)
                ef[k] = __expf(flds[wv][(gb + k) & 31][lane]);
            // stage 16 ahead (slots (gb+16+k)&31 - disjoint from reads)
            #pragma unroll
            for (int k = 0; k < 8; ++k) {
                int ts = gb + 16 + k;
                ts = ts > SEQ - 1 ? SEQ - 1 : ts;       // tail: dummy restage
                stage4(gbase + (size_t)((unsigned)ts * (unsigned)EMROW),
                       (float*)&flds[wv][(gb + 16 + k) & 31][0]);
            }
            // 8 recursion steps, phase-split broadcast
            #pragma unroll
            for (int k = 0; k < 8; ++k) {
                int uu = __float_as_int(u);
                // phase 1: 54 back-to-back readlanes -> SGPRs
                int s0,s1,s2,s3,s4,s5,s6,s7,s8,s9,s10,s11,s12,s13;
                int s14,s15,s16,s17,s18,s19,s20,s21,s22,s23,s24,s25,s26,s27;
                int s28,s29,s30,s31,s32,s33,s34,s35,s36,s37,s38,s39,s40,s41;
                int s42,s43,s44,s45,s46,s47,s48,s49,s50,s51,s52,s53;
                #define RL(n) s##n = __builtin_amdgcn_readlane(uu, n)
                RL(0);RL(1);RL(2);RL(3);RL(4);RL(5);RL(6);RL(7);
                RL(8);RL(9);RL(10);RL(11);RL(12);RL(13);RL(14);RL(15);
                RL(16);RL(17);RL(18);RL(19);RL(20);RL(21);RL(22);RL(23);
                RL(24);RL(25);RL(26);RL(27);RL(28);RL(29);RL(30);RL(31);
                RL(32);RL(33);RL(34);RL(35);RL(36);RL(37);RL(38);RL(39);
                RL(40);RL(41);RL(42);RL(43);RL(44);RL(45);RL(46);RL(47);
                RL(48);RL(49);RL(50);RL(51);RL(52);RL(53);
                #undef RL
                __builtin_amdgcn_sched_barrier(0);
                // phase 2: 54 back-to-back FMAs (SGPR sources retired)
                float a0 = 0.f, a1 = 0.f, a2 = 0.f, a3 = 0.f;
                #define FM(n, acc) acc = fmaf(E[n], __int_as_float(s##n), acc)
                FM(0,a0);FM(1,a1);FM(2,a2);FM(3,a3);
                FM(4,a0);FM(5,a1);FM(6,a2);FM(7,a3);
                FM(8,a0);FM(9,a1);FM(10,a2);FM(11,a3);
                FM(12,a0);FM(13,a1);FM(14,a2);FM(15,a3);
                FM(16,a0);FM(17,a1);FM(18,a2);FM(19,a3);
                FM(20,a0);FM(21,a1);FM(22,a2);FM(23,a3);
                FM(24,a0);FM(25,a1);FM(26,a2);FM(27,a3);
                FM(28,a0);FM(29,a1);FM(30,a2);FM(31,a3);
                FM(32,a0);FM(33,a1);FM(34,a2);FM(35,a3);
                FM(36,a0);FM(37,a1);FM(38,a2);FM(39,a3);
                FM(40,a0);FM(41,a1);FM(42,a2);FM(43,a3);
                FM(44,a0);FM(45,a1);FM(46,a2);FM(47,a3);
                FM(48,a0);FM(49,a1);FM(50,a2);FM(51,a3);
                FM(52,a0);FM(53,a1);
                #undef FM
                float w  = (a0 + a1) + (a2 + a3);
                float un = w * (ef[k] * __uint_as_float((unsigned)(127 - e_lag) << 23));
                bool  up = ((cur & 1ull) != 0ull) && (lane < NTAG);
                u = up ? un : u;
                esum += up ? e_lag : 0;
                cur >>= 1;
                int ub = __builtin_amdgcn_readlane(__float_as_int(u), 0);
                int en = ((ub >> 23) & 255) - 127;
                e_lag = en < -40 ? -40 : (en > 40 ? 40 : en);
            }
        }
        #pragma unroll
        for (int r = 0; r < 7; ++r) B[r] = B[r + 1];
    }

    // --- final forward score: log(sum_j u[j]*exp(trans[STOP,j])) + esum*ln2 ---
    float us = u * estop;
    #pragma unroll
    for (int off = 32; off >= 1; off >>= 1) us += __shfl_xor(us, off);
    float fwd = __logf(us) + (float)esum * 0.69314718f;

    asm volatile("s_waitcnt vmcnt(0)" ::: "memory");   // clean counter state
    int li   = (msump > 0) ? (msump - 1) : 0;
    int ltag = tags[li * BATCH + b];
    float gold = goldp + tlds[TSTOP * NTAG + ltag];

    if (lane == 0) { part[b] = fwd - gold; msum[b] = msump; }
}

// ---------------------------------------------------------------------------
// Kernel 2: deterministic reduction  out = sum(part) / sum(msum)
// ---------------------------------------------------------------------------
__global__ __launch_bounds__(256) void crf_reduce_kernel(
    const float* __restrict__ part, const int* __restrict__ msum,
    float* __restrict__ out)
{
    const int tid = threadIdx.x;
    float s = 0.f;
    int   m = 0;
    for (int k = tid; k < BATCH; k += 256) { s += part[k]; m += msum[k]; }
    #pragma unroll
    for (int off = 32; off >= 1; off >>= 1) {
        s += __shfl_xor(s, off);
        m += __shfl_xor(m, off);
    }
    __shared__ float sl[4];
    __shared__ int   ml[4];
    if ((tid & 63) == 0) { sl[tid >> 6] = s; ml[tid >> 6] = m; }
    __syncthreads();
    if (tid == 0)
        out[0] = (sl[0] + sl[1] + sl[2] + sl[3]) /
                 (float)(ml[0] + ml[1] + ml[2] + ml[3]);
}

extern "C" void kernel_launch(void* const* d_in, const int* in_sizes, int n_in,
                              void* d_out, int out_size, void* d_ws, size_t ws_size,
                              hipStream_t stream)
{
    const float* em   = (const float*)d_in[0];
    const float* tr   = (const float*)d_in[1];
    const int*   tags = (const int*)d_in[2];
    const int*   mask = (const int*)d_in[3];

    float* part  = (float*)d_ws;
    int*   msumw = (int*)((char*)d_ws + BATCH * sizeof(float));
    float* out   = (float*)d_out;

    crf_fwd_kernel<<<BATCH / NW, 64 * NW, 0, stream>>>(em, tr, tags, mask, part, msumw);
    crf_reduce_kernel<<<1, 256, 0, stream>>>(part, msumw, out);
}